// Round 1
// baseline (20.776 us; speedup 1.0000x reference)
//
#include <hip/hip_runtime.h>

// Problem constants (from reference): B=128, P=2048, N=256, D=2
constexpr int B  = 128;
constexpr int P  = 2048;
constexpr int N  = 256;
constexpr int NT = 16;          // centers per block
constexpr int TPB = 256;        // threads per block
constexpr int PITER = P / TPB;  // 8 p-iterations per thread

__global__ __launch_bounds__(TPB)
void SLayerRational_43190191128606_kernel(
    const float* __restrict__ batch,      // (B, P, 2)
    const float* __restrict__ not_dummy,  // (B, P)
    const float* __restrict__ centers,    // (N, 2)
    const float* __restrict__ sharpness,  // (N, 2)
    const float* __restrict__ exponent,   // (1,)
    float* __restrict__ out)              // (B, N)
{
    const int b   = blockIdx.x >> 4;          // 16 n-tiles per batch row
    const int n0  = (blockIdx.x & 15) * NT;
    const int tid = threadIdx.x;

    // Block-uniform center params -> registers (compiler emits scalar loads)
    float c0[NT], c1[NT], a0[NT], a1[NT];
#pragma unroll
    for (int i = 0; i < NT; ++i) {
        c0[i] = centers[(n0 + i) * 2 + 0];
        c1[i] = centers[(n0 + i) * 2 + 1];
        a0[i] = fabsf(sharpness[(n0 + i) * 2 + 0]);
        a1[i] = fabsf(sharpness[(n0 + i) * 2 + 1]);
    }
    const float e = exponent[0];

    float acc[NT];
#pragma unroll
    for (int i = 0; i < NT; ++i) acc[i] = 0.0f;

    const float2* bb = reinterpret_cast<const float2*>(batch) + (size_t)b * P;
    const float*  nd = not_dummy + (size_t)b * P;

    if (e == 1.0f) {
        // Fast path: r = w / (1 + s)
#pragma unroll 2
        for (int k = 0; k < PITER; ++k) {
            const int p = tid + k * TPB;
            const float2 x = bb[p];          // coalesced float2
            const float  w = nd[p];
#pragma unroll
            for (int i = 0; i < NT; ++i) {
                // abs() folds into VALU input modifiers
                float s = fmaf(fabsf(c0[i] - x.x), a0[i],
                               fabsf(c1[i] - x.y) * a1[i]);
                float r = __builtin_amdgcn_rcpf(1.0f + s);
                acc[i] = fmaf(w, r, acc[i]);
            }
        }
    } else {
        // General path: r = w / (1 + s^e)
        for (int k = 0; k < PITER; ++k) {
            const int p = tid + k * TPB;
            const float2 x = bb[p];
            const float  w = nd[p];
#pragma unroll
            for (int i = 0; i < NT; ++i) {
                float s = fmaf(fabsf(c0[i] - x.x), a0[i],
                               fabsf(c1[i] - x.y) * a1[i]);
                float r = w / (1.0f + powf(s, e));
                acc[i] += r;
            }
        }
    }

    // Intra-wave tree reduction (64 lanes)
#pragma unroll
    for (int i = 0; i < NT; ++i) {
#pragma unroll
        for (int off = 32; off > 0; off >>= 1)
            acc[i] += __shfl_down(acc[i], off, 64);
    }

    // Cross-wave reduction via tiny LDS tile
    __shared__ float red[4][NT];
    const int wave = tid >> 6;
    const int lane = tid & 63;
    if (lane == 0) {
#pragma unroll
        for (int i = 0; i < NT; ++i) red[wave][i] = acc[i];
    }
    __syncthreads();

    if (tid < NT) {
        float ssum = red[0][tid] + red[1][tid] + red[2][tid] + red[3][tid];
        out[b * N + n0 + tid] = ssum;
    }
}

extern "C" void kernel_launch(void* const* d_in, const int* in_sizes, int n_in,
                              void* d_out, int out_size, void* d_ws, size_t ws_size,
                              hipStream_t stream) {
    const float* batch     = (const float*)d_in[0];
    const float* not_dummy = (const float*)d_in[1];
    const float* centers   = (const float*)d_in[2];
    const float* sharpness = (const float*)d_in[3];
    const float* exponent  = (const float*)d_in[4];
    float* out = (float*)d_out;

    const int blocks = B * (N / NT);  // 2048
    SLayerRational_43190191128606_kernel<<<blocks, TPB, 0, stream>>>(
        batch, not_dummy, centers, sharpness, exponent, out);
}